// Round 1
// baseline (4824.281 us; speedup 1.0000x reference)
//
#include <hip/hip_runtime.h>

#define NN 4096
#define QQ 2048
#define LDM 8192
#define GOFF 16384  // float offset of G inside ws

// ---------- helpers ----------
__device__ __forceinline__ float erfinv_f(float x){
  float w = -logf((1.0f - x)*(1.0f + x));
  float p;
  if (w < 5.0f) {
    w = w - 2.5f;
    p = 2.81022636e-08f;
    p = fmaf(p, w, 3.43273939e-07f);
    p = fmaf(p, w, -3.5233877e-06f);
    p = fmaf(p, w, -4.39150654e-06f);
    p = fmaf(p, w, 0.00021858087f);
    p = fmaf(p, w, -0.00125372503f);
    p = fmaf(p, w, -0.00417768164f);
    p = fmaf(p, w, 0.246640727f);
    p = fmaf(p, w, 1.50140941f);
  } else {
    w = sqrtf(w) - 3.0f;
    p = -0.000200214257f;
    p = fmaf(p, w, 0.000100950558f);
    p = fmaf(p, w, 0.00134934322f);
    p = fmaf(p, w, -0.00367342844f);
    p = fmaf(p, w, 0.00573950773f);
    p = fmaf(p, w, -0.0076224613f);
    p = fmaf(p, w, 0.00943887047f);
    p = fmaf(p, w, 1.00167406f);
    p = fmaf(p, w, 2.83297682f);
  }
  return p * x;
}

__device__ __forceinline__ float wave_red(float v){
  #pragma unroll
  for (int o = 32; o > 0; o >>= 1) v += __shfl_down(v, o, 64);
  return v;
}

// ---------- stage 1: per-element stats, bincount ----------
__global__ void k_stats(const float* yt, const float* yp, const float* p_s2e, const float* p_s2b,
                        const int* zi, float* scal, float* t, int* cnt){
  int i = blockIdx.x*blockDim.x + threadIdx.x;
  float s2 = p_s2e[0] + p_s2b[0];
  float y  = (yt[i]-yp[i]) / (0.779696801233676f * sqrtf(s2)) + 0.5772156649015329f;
  float em = expf(-y);
  float u  = expf(-em);
  u = fminf(fmaxf(u, 1e-6f), 1.0f - 1e-6f);
  float zs = 1.41421356237309515f * erfinv_f(2.0f*u - 1.0f);
  int q = zi[i];
  atomicAdd(&t[q], zs);
  atomicAdd(&cnt[q], 1);
  float r0 = wave_red(y), r1 = wave_red(em), r2 = wave_red(zs*zs);
  if ((threadIdx.x & 63) == 0) {
    atomicAdd(&scal[0], r0);  // sum y
    atomicAdd(&scal[1], r1);  // sum exp(-y)
    atomicAdd(&scal[2], r2);  // ss = sum zs^2
  }
}

__global__ void k_make_tt(const float* t, const int* cnt, float* tt, float* rv, float* sc, float* scal){
  int q = blockIdx.x*blockDim.x + threadIdx.x;
  int c = cnt[q];
  float scf = sqrtf((float)c);
  float tv = (c > 0) ? t[q]/scf : 0.0f;
  sc[q] = scf; tt[q] = tv; rv[q] = tv;
  float rd = wave_red(tv*tv);
  if ((threadIdx.x & 63) == 0) atomicAdd(&scal[3], rd);  // ttdot
}

// ---------- stage 2: build G = sig2e*I + sqrt(c_p c_q) * sig2bs * exp(-M/(2l)) ----------
__global__ void k_build_G(const float* dm, const float* sc, const float* p_s2e, const float* p_s2b,
                          const float* p_len, float* G){
  int idx = blockIdx.x*blockDim.x + threadIdx.x;
  int p = idx >> 11, q = idx & (QQ-1);
  float inv2l = 0.5f / p_len[0];
  float v = sc[p]*sc[q]*p_s2b[0]*expf(-dm[(size_t)p*LDM + q]*inv2l);
  if (p == q) v += p_s2e[0];
  G[idx] = v;
}

// ---------- stage 3: blocked Cholesky (NB=128), lower triangle only ----------
// Column-major lower 128x128 tile in LDS: elem(i,j) = s[j*128+i], j<=i.
// Raw outer-product form: no scaled-column race, 1 barrier per column.
__global__ __launch_bounds__(512) void k_factor(float* G, float* scal, int k0){
  __shared__ float s[128*128];   // exactly 64 KB
  int tid = threadIdx.x;
  int r = tid >> 2, h = tid & 3;
  {
    const float* src = &G[(size_t)(k0+r)*QQ + k0];
    for (int j = h; j <= r; j += 4) s[j*128 + r] = src[j];
  }
  __syncthreads();
  int i = r;
  for (int j = 0; j < 127; ++j) {
    float invd = 1.0f / s[j*128 + j];
    if (i > j) {
      float ci = s[j*128 + i] * invd;
      for (int m = j+1+h; m <= i; m += 4) s[m*128 + i] -= ci * s[j*128 + m];
    }
    __syncthreads();
  }
  if (tid == 0) {            // logdetG contribution: 2*sum(log L_jj) = sum(log raw_jj)
    float acc = 0.0f;
    for (int j = 0; j < 128; ++j) acc += logf(s[j*128 + j]);
    atomicAdd(&scal[4], acc);
  }
  if (tid >= 1 && tid < 128) s[tid*128 + 0] = sqrtf(s[tid*128 + tid]); // stash diag roots in unused row-0 slots
  __syncthreads();
  float d0 = sqrtf(s[0]);
  {
    float* dst = &G[(size_t)(k0+r)*QQ + k0];
    for (int j = h; j <= r; j += 4) {
      float dj = (j == 0) ? d0 : s[j*128 + 0];
      dst[j] = (j == r) ? dj : s[j*128 + r]/dj;
    }
  }
}

// invert the two 64x64 diagonal sub-blocks of L in place (W1, W2)
__global__ __launch_bounds__(64) void k_inv64(float* G, int k0){
  __shared__ float l[64*65];
  __shared__ float w[64*65];
  int base = k0 + 64*(int)blockIdx.x;
  int tid = threadIdx.x;
  {
    const float* src = &G[(size_t)(base+tid)*QQ + base];
    for (int j = 0; j <= tid; ++j) l[tid*65 + j] = src[j];
  }
  __syncthreads();
  int j = tid;  // own column of W
  w[j*65 + j] = 1.0f / l[j*65 + j];
  for (int i2 = j+1; i2 < 64; ++i2) {
    float acc = 0.0f;
    for (int m = j; m < i2; ++m) acc += l[i2*65 + m] * w[m*65 + j];
    w[i2*65 + j] = -acc / l[i2*65 + i2];
  }
  __syncthreads();
  for (int idx = tid; idx < 64*64; idx += 64) {
    int i = idx >> 6, jj = idx & 63;
    if (jj <= i) G[(size_t)(base+i)*QQ + base + jj] = w[i*65 + jj];
  }
}

// W21 = -W2 * (B * W1), overwrites B = L21 sub-block.  Full 128x128 W now lives in the diag block.
__global__ __launch_bounds__(256) void k_w21(float* G, int k0){
  __shared__ float w1[64*65];
  __shared__ float w2[64*65];
  __shared__ float tb[64*65];
  int tid = threadIdx.x;
  for (int idx = tid; idx < 64*64; idx += 256) {
    int i = idx >> 6, j = idx & 63;
    w1[i*65+j] = (j <= i) ? G[(size_t)(k0+i)*QQ + k0 + j] : 0.0f;
    w2[i*65+j] = (j <= i) ? G[(size_t)(k0+64+i)*QQ + k0+64 + j] : 0.0f;
  }
  __syncthreads();
  int i = tid & 63, jg = tid >> 6;                 // 4 groups of 16 columns
  const float* brow = &G[(size_t)(k0+64+i)*QQ + k0];
  float acc[16];
  #pragma unroll
  for (int a = 0; a < 16; ++a) acc[a] = 0.0f;
  for (int m = 0; m < 64; ++m) {
    float bv = brow[m];
    #pragma unroll
    for (int a = 0; a < 16; ++a) acc[a] += bv * w1[m*65 + jg*16 + a];
  }
  #pragma unroll
  for (int a = 0; a < 16; ++a) tb[i*65 + jg*16 + a] = acc[a];
  __syncthreads();
  #pragma unroll
  for (int a = 0; a < 16; ++a) acc[a] = 0.0f;
  for (int m = 0; m <= i; ++m) {
    float wv = w2[i*65 + m];
    #pragma unroll
    for (int a = 0; a < 16; ++a) acc[a] += wv * tb[m*65 + jg*16 + a];
  }
  float* dst = &G[(size_t)(k0+64+i)*QQ + k0];
  #pragma unroll
  for (int a = 0; a < 16; ++a) dst[jg*16 + a] = -acc[a];
}

// panel "TRSM" as GEMM: P = A21 * W^T  (in place over A21; each block owns 64 rows x all 128 cols)
__global__ __launch_bounds__(256) void k_trsm(float* G, int k0){
  __shared__ alignas(16) float AT[64*68];    // [m][i]
  __shared__ alignas(16) float WT[64*132];   // [m][j], zero-filled above diagonal
  int tid = threadIdx.x;
  int rowbase = k0 + 128 + 64*(int)blockIdx.x;
  int ty = tid >> 4, tx = tid & 15;
  float acc[4][8];
  #pragma unroll
  for (int a = 0; a < 4; ++a)
    #pragma unroll
    for (int b = 0; b < 8; ++b) acc[a][b] = 0.0f;
  for (int kc = 0; kc < 128; kc += 64) {
    for (int idx = tid; idx < 64*64; idx += 256) {
      int m = idx & 63, ii = idx >> 6;
      AT[m*68 + ii] = G[(size_t)(rowbase+ii)*QQ + k0 + kc + m];
    }
    for (int idx = tid; idx < 64*128; idx += 256) {
      int m = idx & 63, j = idx >> 6;
      WT[m*132 + j] = (kc + m <= j) ? G[(size_t)(k0+j)*QQ + k0 + kc + m] : 0.0f;
    }
    __syncthreads();
    for (int m = 0; m < 64; ++m) {
      float4 av = *(const float4*)&AT[m*68 + ty*4];
      float4 b0 = *(const float4*)&WT[m*132 + tx*8];
      float4 b1 = *(const float4*)&WT[m*132 + tx*8 + 4];
      float avv[4] = {av.x, av.y, av.z, av.w};
      float bvv[8] = {b0.x, b0.y, b0.z, b0.w, b1.x, b1.y, b1.z, b1.w};
      #pragma unroll
      for (int a = 0; a < 4; ++a)
        #pragma unroll
        for (int b = 0; b < 8; ++b) acc[a][b] += avv[a]*bvv[b];
    }
    __syncthreads();
  }
  #pragma unroll
  for (int a = 0; a < 4; ++a)
    #pragma unroll
    for (int b = 0; b < 8; ++b)
      G[(size_t)(rowbase + ty*4 + a)*QQ + k0 + tx*8 + b] = acc[a][b];
}

// trailing update: C -= P P^T on lower-triangle 64x64 tiles
__global__ __launch_bounds__(256) void k_syrk(float* G, int k0){
  __shared__ alignas(16) float PT1[64*68];
  __shared__ alignas(16) float PT2[64*68];
  int b = blockIdx.x;
  int ti = (int)((sqrtf(8.0f*(float)b + 1.0f) - 1.0f)*0.5f);
  while ((ti+1)*(ti+2)/2 <= b) ++ti;
  while (ti*(ti+1)/2 > b) --ti;
  int tj = b - ti*(ti+1)/2;
  int ibase = k0 + 128 + ti*64, jbase = k0 + 128 + tj*64;
  int tid = threadIdx.x, ty = tid >> 4, tx = tid & 15;
  float acc[4][4];
  #pragma unroll
  for (int a = 0; a < 4; ++a)
    #pragma unroll
    for (int c = 0; c < 4; ++c) acc[a][c] = 0.0f;
  for (int kc = 0; kc < 128; kc += 64) {
    for (int idx = tid; idx < 64*64; idx += 256) {
      int m = idx & 63, ii = idx >> 6;
      PT1[m*68 + ii] = G[(size_t)(ibase+ii)*QQ + k0 + kc + m];
      PT2[m*68 + ii] = G[(size_t)(jbase+ii)*QQ + k0 + kc + m];
    }
    __syncthreads();
    for (int m = 0; m < 64; ++m) {
      float4 av = *(const float4*)&PT1[m*68 + ty*4];
      float4 bv = *(const float4*)&PT2[m*68 + tx*4];
      float avv[4] = {av.x, av.y, av.z, av.w};
      float bvv[4] = {bv.x, bv.y, bv.z, bv.w};
      #pragma unroll
      for (int a = 0; a < 4; ++a)
        #pragma unroll
        for (int c = 0; c < 4; ++c) acc[a][c] += avv[a]*bvv[c];
    }
    __syncthreads();
  }
  #pragma unroll
  for (int a = 0; a < 4; ++a)
    #pragma unroll
    for (int c = 0; c < 4; ++c)
      G[(size_t)(ibase + ty*4 + a)*QQ + jbase + tx*4 + c] -= acc[a][c];
}

// ---------- stage 4: blocked triangular solves with inverted diag blocks ----------
__global__ __launch_bounds__(128) void k_fsolve(const float* G, const float* rv, float* xv, int k0){
  int i = threadIdx.x;
  const float* row = &G[(size_t)(k0+i)*QQ + k0];
  float acc = 0.0f;
  for (int j = 0; j <= i; ++j) acc += row[j]*rv[k0+j];
  xv[k0+i] = acc;
}

__global__ void k_fupdate(const float* G, float* rv, const float* xv, int k0){
  __shared__ float sx[128];
  if (threadIdx.x < 128) sx[threadIdx.x] = xv[k0 + threadIdx.x];
  __syncthreads();
  int i = k0 + 128 + blockIdx.x*blockDim.x + threadIdx.x;
  if (i < QQ) {
    const float* row = &G[(size_t)i*QQ + k0];
    float acc = 0.0f;
    for (int j = 0; j < 128; ++j) acc += row[j]*sx[j];
    rv[i] -= acc;
  }
}

__global__ __launch_bounds__(128) void k_bsolve(const float* G, float* xv, int k0){
  __shared__ float sx[128];
  int i = threadIdx.x;
  sx[i] = xv[k0+i];
  __syncthreads();
  float acc = 0.0f;
  for (int j = i; j < 128; ++j) acc += G[(size_t)(k0+j)*QQ + k0 + i]*sx[j];
  xv[k0+i] = acc;
}

__global__ void k_bupdate(const float* G, float* xv, int k0){
  __shared__ float sx[128];
  if (threadIdx.x < 128) sx[threadIdx.x] = xv[k0 + threadIdx.x];
  __syncthreads();
  int col = blockIdx.x*blockDim.x + threadIdx.x;
  if (col < k0) {
    float acc = 0.0f;
    for (int r2 = 0; r2 < 128; ++r2) acc += G[(size_t)(k0+r2)*QQ + col]*sx[r2];
    xv[col] -= acc;
  }
}

__global__ void k_dot(const float* tt, const float* xv, float* scal){
  int q = blockIdx.x*blockDim.x + threadIdx.x;
  float rd = wave_red(tt[q]*xv[q]);
  if ((threadIdx.x & 63) == 0) atomicAdd(&scal[5], rd);
}

__global__ void k_final(const float* scal, const float* p_s2e, const float* p_s2b, float* out){
  float s2e = p_s2e[0], s2b = p_s2b[0], s2 = s2e + s2b;
  const float Nf = 4096.0f, Qf = 2048.0f;
  float mld = 2.0f*scal[0] + 2.0f*scal[1] + Nf*logf(s2) + Nf*logf(0.6079271018540267f);
  float quad = (s2/s2e)*(scal[2] - scal[3] + s2e*scal[5]);
  float logdetR = Nf*logf(s2e) - Nf*logf(s2) - Qf*logf(s2e) + scal[4];
  out[0] = mld + quad - scal[2] + logdetR;
}

// ---------- launch ----------
extern "C" void kernel_launch(void* const* d_in, const int* in_sizes, int n_in,
                              void* d_out, int out_size, void* d_ws, size_t ws_size,
                              hipStream_t stream){
  const float* yt  = (const float*)d_in[0];
  const float* yp  = (const float*)d_in[1];
  const float* s2e = (const float*)d_in[2];
  const float* s2b = (const float*)d_in[3];
  const float* len = (const float*)d_in[4];
  const float* dm  = (const float*)d_in[5];
  const int*   zi  = (const int*)d_in[6];
  float* ws   = (float*)d_ws;
  float* scal = ws;
  float* t    = ws + 16;
  float* tt   = ws + 16 + QQ;
  float* rv   = ws + 16 + 2*QQ;
  float* xv   = ws + 16 + 3*QQ;
  float* sc   = ws + 16 + 4*QQ;
  int*   cnt  = (int*)(ws + 16 + 5*QQ);
  float* G    = ws + GOFF;
  float* out  = (float*)d_out;

  hipMemsetAsync(d_ws, 0, GOFF*sizeof(float), stream);
  k_stats  <<<NN/256, 256, 0, stream>>>(yt, yp, s2e, s2b, zi, scal, t, cnt);
  k_make_tt<<<QQ/256, 256, 0, stream>>>(t, cnt, tt, rv, sc, scal);
  k_build_G<<<(QQ*QQ)/256, 256, 0, stream>>>(dm, sc, s2e, s2b, len, G);

  for (int s = 0; s < 16; ++s) {
    int k0 = s*128, m = QQ - k0 - 128;
    k_factor<<<1, 512, 0, stream>>>(G, scal, k0);
    k_inv64 <<<2,  64, 0, stream>>>(G, k0);
    k_w21   <<<1, 256, 0, stream>>>(G, k0);
    if (m > 0) {
      int nt = m/64;
      k_trsm<<<nt, 256, 0, stream>>>(G, k0);
      k_syrk<<<nt*(nt+1)/2, 256, 0, stream>>>(G, k0);
    }
  }
  for (int s = 0; s < 16; ++s) {
    int k0 = s*128, m = QQ - k0 - 128;
    k_fsolve<<<1, 128, 0, stream>>>(G, rv, xv, k0);
    if (m > 0) k_fupdate<<<(m+255)/256, 256, 0, stream>>>(G, rv, xv, k0);
  }
  for (int s = 15; s >= 0; --s) {
    int k0 = s*128;
    k_bsolve<<<1, 128, 0, stream>>>(G, xv, k0);
    if (k0 > 0) k_bupdate<<<(k0+255)/256, 256, 0, stream>>>(G, xv, k0);
  }
  k_dot  <<<QQ/256, 256, 0, stream>>>(tt, xv, scal);
  k_final<<<1, 1, 0, stream>>>(scal, s2e, s2b, out);
}